// Round 12
// baseline (189.499 us; speedup 1.0000x reference)
//
#include <hip/hip_runtime.h>

#define TT    2000
#define NG    4000
#define WARM  365
#define LENF  15
#define NPHY  12
#define BLK   30                  // timesteps per staged block
#define SLOTW 64                  // dwords per step in stage LDS (48 used + pad)
#define SLOTD (BLK * SLOTW)       // 1920 dwords per stage slot
#define NBLK  67                  // 67*30 = 2010 steps (covers TT, stores gated)
#define RING  (BLK * 64)          // 1920 dwords per handoff ring slot

typedef const float __attribute__((address_space(1)))* gptr_t;
typedef float __attribute__((address_space(3)))* lptr_t;
typedef __attribute__((ext_vector_type(2))) float f32x2;

// LDS byte-address of a __shared__ element (32-bit, for asm ds_read)
__device__ __forceinline__ uint32_t lds_addr(const float* p) {
    return (uint32_t)(uintptr_t)(lptr_t)p;
}

#define DS_WAIT_FENCE() do { \
    asm volatile("s_waitcnt lgkmcnt(0)" ::: "memory"); \
    __builtin_amdgcn_sched_barrier(0); } while (0)

// Quad-wide sum via DPP (VALU-only; no LDS pipe).
__device__ __forceinline__ float quad_sum(float x) {
    int a = __builtin_amdgcn_update_dpp(0, __float_as_int(x), 0xB1, 0xF, 0xF, true);
    float s = x + __int_as_float(a);
    int b = __builtin_amdgcn_update_dpp(0, __float_as_int(s), 0x4E, 0xF, 0xF, true);
    return s + __int_as_float(b);
}

// Raw barrier: wait own ds ops, then barrier. NO vmcnt drain — wave0's
// global_load_lds prefetch queue must survive (T4 counted-vmcnt pattern).
#define WG_BARRIER() asm volatile("s_waitcnt lgkmcnt(0)\n\ts_barrier" ::: "memory")

// Wave-specialized pipeline: 4 waves / workgroup on 4 SIMDs of one CU.
//   wave0: stage loads + snow chain (block i)      -> s_rt ring
//   wave1: soil-moisture chain      (block i-1)    -> s_rex ring
//   wave2: response chain + quad mean (block i-2)  -> s_q ring
//   wave3: 15-tap routing conv + stores (block i-3)
// r12: ring/stage reads are inline-asm ds_read batches in plain unrolled
// loops (volatile order = back-to-back issue, one lgkmcnt(0), forced register
// residency) — r9/r10 showed the compiler re-sinks C-level reads into the
// chains (~120cyc/step); r11's template/lambda vehicle failed to compile.
__global__ __launch_bounds__(256, 1) void hbv_pipe_kernel(
    const float* __restrict__ xphy,   // [T, G, 3]
    const float* __restrict__ prm,    // [1, G, 50]
    float* __restrict__ out)          // [T-WARM, G]
{
    __shared__ float s_stage[4 * SLOTD];  // 30720 B input stage ring
    __shared__ float s_rt [2 * RING];     // snow -> soil      (15360 B)
    __shared__ float s_rex[2 * RING];     // soil -> response  (15360 B)
    __shared__ float s_q  [2 * RING];     // response -> conv  (15360 B)

    const int lane = threadIdx.x & 63;
    const int wid  = threadIdx.x >> 6;    // 0..3
    const int g0   = blockIdx.x * 16;     // 250 workgroups * 16 cells
    const int g    = g0 + (lane >> 2);
    const int m    = lane & 3;

    const float* pg = prm + (size_t)g * (NPHY * 4 + 2);

    const float lb[NPHY] = {1.0f, 50.0f, 0.05f, 0.01f, 0.001f, 0.2f, 0.0f, 0.0f, -2.5f, 0.5f, 0.0f, 0.0f};
    const float ub[NPHY] = {6.0f, 1000.0f, 0.9f, 0.5f, 0.2f, 1.0f, 10.0f, 100.0f, 2.5f, 10.0f, 0.1f, 0.2f};
    float ph[NPHY];
    #pragma unroll
    for (int i = 0; i < NPHY; ++i)
        ph[i] = lb[i] + pg[i * 4 + m] * (ub[i] - lb[i]);

    const float beta = ph[0], fc = ph[1], k0 = ph[2], k1 = ph[3], k2 = ph[4],
                lp = ph[5], perc = ph[6], uzl = ph[7], ttp = ph[8],
                cfmax = ph[9], cfr = ph[10], cwh = ph[11];
    const float rfc    = 1.0f / fc;
    const float rlpfc  = 1.0f / (lp * fc);
    const float cfrcf  = cfr * cfmax;
    const float blfc   = beta * __builtin_amdgcn_logf(rfc);  // beta*log2(1/fc)
    const float onemk1 = 1.0f - k1;
    const float onemk2 = 1.0f - k2;

    // Routing weights (gammaln / th^aa cancel under normalization);
    // 0.25 multiplier mean folded in.
    const float aa  = fmaxf(pg[48] * 2.9f, 0.0f) + 0.1f;
    const float th  = fmaxf(pg[49] * 6.5f, 0.0f) + 0.5f;
    const float rth = 1.0f / th;
    const float LOG2E = 1.4426950408889634f;
    float w[LENF];
    float wsum = 0.0f;
    #pragma unroll
    for (int k = 0; k < LENF; ++k) {
        const float tg = (float)k + 0.5f;
        const float e = (aa - 1.0f) * __builtin_log2f(tg) - tg * rth * LOG2E;
        w[k] = __builtin_amdgcn_exp2f(e);
        wsum += w[k];
    }
    const float rw = 0.25f / wsum;
    #pragma unroll
    for (int k = 0; k < LENF; ++k) w[k] *= rw;

    // Per-wave persistent states
    float snowpack = 0.001f, meltwater = 0.001f;   // wave0
    float sm = 0.001f;                             // wave1
    float suz = 0.001f, slz = 0.001f;              // wave2
    float qh[BLK + LENF - 1];                      // wave3: q history (static idx)
    #pragma unroll
    for (int d = 0; d < BLK + LENF - 1; ++d) qh[d] = 0.0f;

    const int loffd = (lane < 48 ? lane : 47);

    auto issue_blk = [&](int b) {
        const int slot = b & 3;
        const int t0 = b * BLK;
        #pragma unroll
        for (int c = 0; c < BLK; ++c) {
            int t = t0 + c;
            if (t > TT - 1) t = TT - 1;
            const float* gsrc = xphy + (size_t)t * (3 * NG) + g0 * 3 + loffd;
            float* ldst = &s_stage[slot * SLOTD + c * SLOTW];
            __builtin_amdgcn_global_load_lds((gptr_t)gsrc, (lptr_t)ldst, 4, 0, 0);
        }
    };

    if (wid == 0) { issue_blk(0); issue_blk(1); }

    for (int i = 0; i <= NBLK + 2; ++i) {
        if (wid == 0) {
            // ---- stage + snow chain, block i ----
            if (i < NBLK) {
                asm volatile("s_waitcnt vmcnt(30)" ::: "memory");  // block i landed
                issue_blk(i + 2);                                  // clamped past end
                const uint32_t sba = lds_addr(&s_stage[(i & 3) * SLOTD + (lane >> 2) * 3]);
                f32x2 pt[BLK];
                #pragma unroll
                for (int j = 0; j < BLK; ++j) {   // (P,T) pairs, back-to-back b64 reads
                    asm volatile("ds_read_b64 %0, %1"
                                 : "=v"(pt[j]) : "v"(sba + j * 256));
                }
                DS_WAIT_FENCE();
                float* rtw = &s_rt[(i & 1) * RING + lane];
                #pragma unroll
                for (int j = 0; j < BLK; ++j) {
                    const float Pt = pt[j][0], Tm = pt[j][1];
                    const float dT      = Tm - ttp;
                    const float rain    = (Tm >= ttp) ? Pt : 0.0f;
                    const float snow    = Pt - rain;
                    const float meltcap = cfmax * fmaxf(dT, 0.0f);
                    const float refcap  = cfrcf * fmaxf(-dT, 0.0f);
                    snowpack += snow;
                    const float melt = fminf(meltcap, snowpack);
                    meltwater += melt;
                    snowpack  -= melt;
                    const float refreeze = fminf(refcap, meltwater);
                    meltwater -= refreeze;
                    snowpack  += refreeze;
                    const float tosoil = fmaxf(fmaf(-cwh, snowpack, meltwater), 0.0f);
                    meltwater -= tosoil;
                    rtw[j * 64] = rain + tosoil;
                }
            }
        } else if (wid == 1) {
            // ---- soil-moisture chain, block i-1 ----
            const int b = i - 1;
            if (b >= 0 && b < NBLK) {
                const uint32_t rta = lds_addr(&s_rt[(b & 1) * RING + lane]);
                const uint32_t sba = lds_addr(&s_stage[(b & 3) * SLOTD + (lane >> 2) * 3]);
                float rt[BLK], ev[BLK];
                #pragma unroll
                for (int j = 0; j < BLK; ++j) {
                    asm volatile("ds_read_b32 %0, %1"
                                 : "=v"(rt[j]) : "v"(rta + j * 256));
                }
                #pragma unroll
                for (int j = 0; j < BLK; ++j) {
                    asm volatile("ds_read_b32 %0, %1"
                                 : "=v"(ev[j]) : "v"(sba + j * 256 + 8));
                }
                DS_WAIT_FENCE();
                float* rexw = &s_rex[(b & 1) * RING + lane];
                #pragma unroll
                for (int j = 0; j < BLK; ++j) {
                    // sw = (sm/fc)^beta = exp2(beta*log2(sm) + beta*log2(1/fc))
                    const float sw    = __builtin_amdgcn_exp2f(fmaf(beta, __builtin_amdgcn_logf(sm), blfc));
                    const float smprt = sm + rt[j];
                    const float sm1   = fmaf(-rt[j], sw, smprt);   // sm + rt*(1-sw)
                    const float sm2   = fminf(sm1, fc);
                    // off-chain: uf = 1 - evapfactor
                    const float uf = fmaxf(fmaf(-ev[j], rlpfc, 1.0f), 0.0f);
                    // sm2 - min(sm2, sm2*(1-uf), ev) = max(sm2*uf, sm2-ev)
                    const float av = sm2 * uf;
                    const float cv = sm2 - ev[j];
                    sm = fmaxf(fmaxf(av, cv), 1e-5f);              // v_max3
                    rexw[j * 64] = fmaf(rt[j], sw, sm1 - sm2);     // recharge + excess
                }
            }
        } else if (wid == 2) {
            // ---- response chain + quad mean, block i-2 ----
            const int b = i - 2;
            if (b >= 0 && b < NBLK) {
                const uint32_t rxa = lds_addr(&s_rex[(b & 1) * RING + lane]);
                float rex[BLK];
                #pragma unroll
                for (int j = 0; j < BLK; ++j) {
                    asm volatile("ds_read_b32 %0, %1"
                                 : "=v"(rex[j]) : "v"(rxa + j * 256));
                }
                DS_WAIT_FENCE();
                float* qw = &s_q[(b & 1) * RING + lane];
                #pragma unroll
                for (int j = 0; j < BLK; ++j) {
                    const float suz1 = suz + rex[j];
                    const float prc  = fminf(suz1, perc);
                    const float suzA = suz1 - prc;
                    const float tq   = fmaxf(suzA - uzl, 0.0f);
                    const float q0   = k0 * tq;
                    const float suzB = fmaf(-k0, tq, suzA);
                    const float q1   = k1 * suzB;
                    suz = suzB * onemk1;
                    const float slz1 = slz + prc;
                    const float q2   = k2 * slz1;
                    slz = slz1 * onemk2;
                    qw[j * 64] = quad_sum(q0 + q1 + q2);   // *0.25 folded into w
                }
            }
        } else {
            // ---- 15-tap routing conv (gather form) + stores, block i-3 ----
            const int b = i - 3;
            if (b >= 0 && b < NBLK) {
                const int t0 = b * BLK;
                const uint32_t qa = lds_addr(&s_q[(b & 1) * RING + lane]);
                #pragma unroll
                for (int j = 0; j < BLK; ++j) {   // read q straight into history window
                    asm volatile("ds_read_b32 %0, %1"
                                 : "=v"(qh[LENF - 1 + j]) : "v"(qa + j * 256));
                }
                DS_WAIT_FENCE();
                float ov[(BLK + 3) / 4];
                #pragma unroll
                for (int k = 0; k < (BLK + 3) / 4; ++k) ov[k] = 0.0f;
                #pragma unroll
                for (int j = 0; j < BLK; ++j) {
                    float o = w[0] * qh[LENF - 1 + j];
                    #pragma unroll
                    for (int k = 1; k < LENF; ++k)
                        o = fmaf(w[k], qh[LENF - 1 + j - k], o);
                    const bool sel = ((j & 3) == m);
                    ov[j >> 2] = sel ? o : ov[j >> 2];     // j>>2 compile-time
                }
                #pragma unroll
                for (int d = 0; d < LENF - 1; ++d) qh[d] = qh[d + BLK];   // static shift
                #pragma unroll
                for (int k = 0; k < (BLK + 3) / 4; ++k) {
                    const int j = k * 4 + m;
                    const int t = t0 + j;
                    if (j < BLK && t >= WARM && t < TT)
                        out[(size_t)(t - WARM) * NG + g] = ov[k];
                }
            }
        }
        WG_BARRIER();
    }
    // drain wave0's leftover in-flight LDS-writing loads before endpgm
    if (wid == 0) asm volatile("s_waitcnt vmcnt(0)" ::: "memory");
}

extern "C" void kernel_launch(void* const* d_in, const int* in_sizes, int n_in,
                              void* d_out, int out_size, void* d_ws, size_t ws_size,
                              hipStream_t stream) {
    const float* xphy = (const float*)d_in[0];   // [2000, 4000, 3]
    const float* prm  = (const float*)d_in[1];   // [1, 4000, 50]
    float* out = (float*)d_out;                  // [1635, 4000, 1]

    hbv_pipe_kernel<<<NG / 16, 256, 0, stream>>>(xphy, prm, out);
}

// Round 13
// 165.544 us; speedup vs baseline: 1.1447x; 1.1447x over previous
//
#include <hip/hip_runtime.h>

#define TT    2000
#define NG    4000
#define WARM  365
#define LENF  15
#define NPHY  12
#define BLK   30                  // timesteps per staged block
#define NC    8                   // grid cells per workgroup (lanes 0..31 active)
#define SLOTW 64                  // dwords per step in stage LDS
#define SLOTD (BLK * SLOTW)       // 1920 dwords per stage slot
#define NBLK  67                  // 67*30 = 2010 steps (covers TT, stores gated)
#define RING  (BLK * 64)          // 1920 dwords per handoff ring slot

typedef const float __attribute__((address_space(1)))* gptr_t;
typedef float __attribute__((address_space(3)))* lptr_t;

// Quad-wide sum via DPP (VALU-only; no LDS pipe).
__device__ __forceinline__ float quad_sum(float x) {
    int a = __builtin_amdgcn_update_dpp(0, __float_as_int(x), 0xB1, 0xF, 0xF, true);
    float s = x + __int_as_float(a);
    int b = __builtin_amdgcn_update_dpp(0, __float_as_int(s), 0x4E, 0xF, 0xF, true);
    return s + __int_as_float(b);
}

// Raw barrier: wait own ds ops, then barrier. NO vmcnt drain — wave0's
// global_load_lds prefetch queue must survive (T4 counted-vmcnt pattern).
#define WG_BARRIER() asm volatile("s_waitcnt lgkmcnt(0)\n\ts_barrier" ::: "memory")

// Wave-specialized pipeline: 4 waves / workgroup.
//   wave0: stage loads + snow chain (block i)      -> s_rt ring
//   wave1: soil-moisture chain      (block i-1)    -> s_rex ring
//   wave2: response chain + quad mean (block i-2)  -> s_q ring
//   wave3: 15-tap routing conv + stores (block i-3)
// r13: occupancy experiment — NC=8 cells/WG (was 16), 500 WGs, 2 WGs/CU
// (2x75KB LDS = 150KB <= 160KB) -> 2 waves/SIMD from independent pipelines.
// r8-r12 showed each wave is ~70% latency-stalled with nothing to fill the
// bubbles (1 wave/SIMD); a second resident workgroup fills them via TLP.
__global__ __launch_bounds__(256, 2) void hbv_pipe_kernel(
    const float* __restrict__ xphy,   // [T, G, 3]
    const float* __restrict__ prm,    // [1, G, 50]
    float* __restrict__ out)          // [T-WARM, G]
{
    __shared__ float s_stage[4 * SLOTD];  // 30720 B input stage ring
    __shared__ float s_rt [2 * RING];     // snow -> soil      (15360 B)
    __shared__ float s_rex[2 * RING];     // soil -> response  (15360 B)
    __shared__ float s_q  [2 * RING];     // response -> conv  (15360 B)

    const int lane = threadIdx.x & 63;
    const int wid  = threadIdx.x >> 6;    // 0..3
    const int g0   = blockIdx.x * NC;     // 500 workgroups * 8 cells
    const int cell = lane >> 2;           // 0..15; only 0..NC-1 are real
    const int g    = g0 + cell;
    const int gp   = (g < NG) ? g : (NG - 1);   // clamped for reads
    const bool cellok = (cell < NC);
    const int m    = lane & 3;

    const float* pg = prm + (size_t)gp * (NPHY * 4 + 2);

    const float lb[NPHY] = {1.0f, 50.0f, 0.05f, 0.01f, 0.001f, 0.2f, 0.0f, 0.0f, -2.5f, 0.5f, 0.0f, 0.0f};
    const float ub[NPHY] = {6.0f, 1000.0f, 0.9f, 0.5f, 0.2f, 1.0f, 10.0f, 100.0f, 2.5f, 10.0f, 0.1f, 0.2f};
    float ph[NPHY];
    #pragma unroll
    for (int i = 0; i < NPHY; ++i)
        ph[i] = lb[i] + pg[i * 4 + m] * (ub[i] - lb[i]);

    const float beta = ph[0], fc = ph[1], k0 = ph[2], k1 = ph[3], k2 = ph[4],
                lp = ph[5], perc = ph[6], uzl = ph[7], ttp = ph[8],
                cfmax = ph[9], cfr = ph[10], cwh = ph[11];
    const float rfc    = 1.0f / fc;
    const float rlpfc  = 1.0f / (lp * fc);
    const float cfrcf  = cfr * cfmax;
    const float blfc   = beta * __builtin_amdgcn_logf(rfc);  // beta*log2(1/fc)
    const float onemk1 = 1.0f - k1;
    const float onemk2 = 1.0f - k2;

    // Routing weights (gammaln / th^aa cancel under normalization);
    // 0.25 multiplier mean folded in.
    const float aa  = fmaxf(pg[48] * 2.9f, 0.0f) + 0.1f;
    const float th  = fmaxf(pg[49] * 6.5f, 0.0f) + 0.5f;
    const float rth = 1.0f / th;
    const float LOG2E = 1.4426950408889634f;
    float w[LENF];
    float wsum = 0.0f;
    #pragma unroll
    for (int k = 0; k < LENF; ++k) {
        const float tg = (float)k + 0.5f;
        const float e = (aa - 1.0f) * __builtin_log2f(tg) - tg * rth * LOG2E;
        w[k] = __builtin_amdgcn_exp2f(e);
        wsum += w[k];
    }
    const float rw = 0.25f / wsum;
    #pragma unroll
    for (int k = 0; k < LENF; ++k) w[k] *= rw;

    // Per-wave persistent states
    float snowpack = 0.001f, meltwater = 0.001f;   // wave0
    float sm = 0.001f;                             // wave1
    float suz = 0.001f, slz = 0.001f;              // wave2
    float qh[BLK + LENF - 1];                      // wave3: q history (static idx)
    #pragma unroll
    for (int d = 0; d < BLK + LENF - 1; ++d) qh[d] = 0.0f;

    // per-lane dword offset within a step's 3*NC-dword panel (clamped pad lanes)
    const int loffd = (lane < 3 * NC ? lane : 3 * NC - 1);

    auto issue_blk = [&](int b) {
        const int slot = b & 3;
        const int t0 = b * BLK;
        #pragma unroll
        for (int c = 0; c < BLK; ++c) {
            int t = t0 + c;
            if (t > TT - 1) t = TT - 1;
            const float* gsrc = xphy + (size_t)t * (3 * NG) + g0 * 3 + loffd;
            float* ldst = &s_stage[slot * SLOTD + c * SLOTW];
            __builtin_amdgcn_global_load_lds((gptr_t)gsrc, (lptr_t)ldst, 4, 0, 0);
        }
    };

    if (wid == 0) { issue_blk(0); issue_blk(1); }

    for (int i = 0; i <= NBLK + 2; ++i) {
        if (wid == 0) {
            // ---- stage + snow chain, block i ----
            if (i < NBLK) {
                asm volatile("s_waitcnt vmcnt(30)" ::: "memory");  // block i landed
                issue_blk(i + 2);                                  // clamped past end
                const float* sb = &s_stage[(i & 3) * SLOTD + cell * 3];
                float P[BLK], Tm[BLK];
                #pragma unroll
                for (int j = 0; j < BLK; ++j) { P[j] = sb[j * SLOTW]; Tm[j] = sb[j * SLOTW + 1]; }
                float* rtw = &s_rt[(i & 1) * RING + lane];
                #pragma unroll
                for (int j = 0; j < BLK; ++j) {
                    const float dT      = Tm[j] - ttp;
                    const float rain    = (Tm[j] >= ttp) ? P[j] : 0.0f;
                    const float snow    = P[j] - rain;
                    const float meltcap = cfmax * fmaxf(dT, 0.0f);
                    const float refcap  = cfrcf * fmaxf(-dT, 0.0f);
                    snowpack += snow;
                    const float melt = fminf(meltcap, snowpack);
                    meltwater += melt;
                    snowpack  -= melt;
                    const float refreeze = fminf(refcap, meltwater);
                    meltwater -= refreeze;
                    snowpack  += refreeze;
                    const float tosoil = fmaxf(fmaf(-cwh, snowpack, meltwater), 0.0f);
                    meltwater -= tosoil;
                    rtw[j * 64] = rain + tosoil;
                }
            }
        } else if (wid == 1) {
            // ---- soil-moisture chain, block i-1 ----
            const int b = i - 1;
            if (b >= 0 && b < NBLK) {
                const float* sb  = &s_stage[(b & 3) * SLOTD + cell * 3];
                const float* rtr = &s_rt[(b & 1) * RING + lane];
                float rt[BLK], ev[BLK], uum1[BLK];
                #pragma unroll
                for (int j = 0; j < BLK; ++j) { rt[j] = rtr[j * 64]; ev[j] = sb[j * SLOTW + 2]; }
                #pragma unroll
                for (int j = 0; j < BLK; ++j)
                    uum1[j] = fmaxf(fmaf(-ev[j], rlpfc, 1.0f), 0.0f);   // 1 - evap factor
                float* rexw = &s_rex[(b & 1) * RING + lane];
                #pragma unroll
                for (int j = 0; j < BLK; ++j) {
                    // sw = (sm/fc)^beta = exp2(beta*log2(sm) + beta*log2(1/fc))
                    const float sw    = __builtin_amdgcn_exp2f(fmaf(beta, __builtin_amdgcn_logf(sm), blfc));
                    const float smprt = sm + rt[j];
                    const float sm1   = fmaf(-rt[j], sw, smprt);   // sm + rt*(1-sw)
                    const float sm2   = fminf(sm1, fc);
                    // sm2 - min(sm2, sm2*uu, ev) = max(sm2*(1-uu), sm2-ev)
                    const float av = sm2 * uum1[j];
                    const float cv = sm2 - ev[j];
                    sm = fmaxf(fmaxf(av, cv), 1e-5f);              // v_max3
                    rexw[j * 64] = fmaf(rt[j], sw, sm1 - sm2);     // recharge + excess
                }
            }
        } else if (wid == 2) {
            // ---- response chain + quad mean, block i-2 ----
            const int b = i - 2;
            if (b >= 0 && b < NBLK) {
                const float* rexr = &s_rex[(b & 1) * RING + lane];
                float rex[BLK];
                #pragma unroll
                for (int j = 0; j < BLK; ++j) rex[j] = rexr[j * 64];
                float* qw = &s_q[(b & 1) * RING + lane];
                #pragma unroll
                for (int j = 0; j < BLK; ++j) {
                    const float suz1 = suz + rex[j];
                    const float prc  = fminf(suz1, perc);
                    const float suzA = suz1 - prc;
                    const float tq   = fmaxf(suzA - uzl, 0.0f);
                    const float q0   = k0 * tq;
                    const float suzB = fmaf(-k0, tq, suzA);
                    const float q1   = k1 * suzB;
                    suz = suzB * onemk1;
                    const float slz1 = slz + prc;
                    const float q2   = k2 * slz1;
                    slz = slz1 * onemk2;
                    qw[j * 64] = quad_sum(q0 + q1 + q2);   // *0.25 folded into w
                }
            }
        } else {
            // ---- 15-tap routing conv (gather form) + stores, block i-3 ----
            const int b = i - 3;
            if (b >= 0 && b < NBLK) {
                const int t0 = b * BLK;
                const float* qr = &s_q[(b & 1) * RING + lane];
                #pragma unroll
                for (int j = 0; j < BLK; ++j) qh[LENF - 1 + j] = qr[j * 64];
                float ov[(BLK + 3) / 4];
                #pragma unroll
                for (int k = 0; k < (BLK + 3) / 4; ++k) ov[k] = 0.0f;
                #pragma unroll
                for (int j = 0; j < BLK; ++j) {
                    float o = w[0] * qh[LENF - 1 + j];
                    #pragma unroll
                    for (int k = 1; k < LENF; ++k)
                        o = fmaf(w[k], qh[LENF - 1 + j - k], o);
                    const bool sel = ((j & 3) == m);
                    ov[j >> 2] = sel ? o : ov[j >> 2];     // j>>2 compile-time
                }
                #pragma unroll
                for (int d = 0; d < LENF - 1; ++d) qh[d] = qh[d + BLK];   // static shift
                #pragma unroll
                for (int k = 0; k < (BLK + 3) / 4; ++k) {
                    const int j = k * 4 + m;
                    const int t = t0 + j;
                    if (cellok && j < BLK && t >= WARM && t < TT)
                        out[(size_t)(t - WARM) * NG + g] = ov[k];
                }
            }
        }
        WG_BARRIER();
    }
    // drain wave0's leftover in-flight LDS-writing loads before endpgm
    if (wid == 0) asm volatile("s_waitcnt vmcnt(0)" ::: "memory");
}

extern "C" void kernel_launch(void* const* d_in, const int* in_sizes, int n_in,
                              void* d_out, int out_size, void* d_ws, size_t ws_size,
                              hipStream_t stream) {
    const float* xphy = (const float*)d_in[0];   // [2000, 4000, 3]
    const float* prm  = (const float*)d_in[1];   // [1, 4000, 50]
    float* out = (float*)d_out;                  // [1635, 4000, 1]

    hbv_pipe_kernel<<<NG / NC, 256, 0, stream>>>(xphy, prm, out);
}

// Round 14
// 126.771 us; speedup vs baseline: 1.4948x; 1.3059x over previous
//
#include <hip/hip_runtime.h>

#define TT    2000
#define NG    4000
#define WARM  365
#define LENF  15
#define NPHY  12
#define BLK   60                  // timesteps per staged block
#define PAIRS (BLK / 2)           // f32x2 pairs per ring slot
#define SLOTW 64                  // dwords per step in stage LDS (48 used + pad)
#define SLOTD (BLK * SLOTW)       // 3840 dwords per stage slot
#define NBLK  34                  // 34*60 = 2040 steps (covers TT, stores gated)
#define ROWF  (3 * NG)            // 12000 floats per timestep row

typedef const float __attribute__((address_space(1)))* gptr_t;
typedef float __attribute__((address_space(3)))* lptr_t;
typedef __attribute__((ext_vector_type(2))) float f32x2;

// Quad-wide sum via DPP (VALU-only; no LDS pipe).
__device__ __forceinline__ float quad_sum(float x) {
    int a = __builtin_amdgcn_update_dpp(0, __float_as_int(x), 0xB1, 0xF, 0xF, true);
    float s = x + __int_as_float(a);
    int b = __builtin_amdgcn_update_dpp(0, __float_as_int(s), 0x4E, 0xF, 0xF, true);
    return s + __int_as_float(b);
}

// Raw barrier: wait own ds ops, then barrier.
#define WG_BARRIER() asm volatile("s_waitcnt lgkmcnt(0)\n\ts_barrier" ::: "memory")

// Wave-specialized pipeline, 4 waves / WG, NC=16 cells (full waves, 250 WGs).
//   wave0: snow chain (block i)        -> s_rt ring (b64 pairs)
//   wave1: soil chain (block i-1)      -> s_rex ring (b64 pairs)
//   wave2: response + quad mean (i-2)  -> s_q ring (b64 pairs)
//   wave3: 15-tap conv + stores (i-3)
// r14: BLK=60 (37 sync events vs 70 — fixed cost ~880cyc/iter halves),
// staging split across ALL 4 waves (15 loads each, incremental addresses),
// 3-deep stage ring + per-iter vmcnt(0) drain (latency still hidden: drain is
// ~10k cyc after issue), b64-paired rings (halve LDS-pipe ops).
__global__ __launch_bounds__(256, 1) void hbv_pipe_kernel(
    const float* __restrict__ xphy,   // [T, G, 3]
    const float* __restrict__ prm,    // [1, G, 50]
    float* __restrict__ out)          // [T-WARM, G]
{
    __shared__ float s_stage[3 * SLOTD];        // 46080 B input stage ring
    __shared__ f32x2 s_rt [2 * PAIRS * 64];     // snow -> soil     (30720 B)
    __shared__ f32x2 s_rex[2 * PAIRS * 64];     // soil -> response (30720 B)
    __shared__ f32x2 s_q  [2 * PAIRS * 64];     // response -> conv (30720 B)

    const int lane = threadIdx.x & 63;
    const int wid  = threadIdx.x >> 6;    // 0..3
    const int g0   = blockIdx.x * 16;     // 250 workgroups * 16 cells
    const int cell = lane >> 2;
    const int g    = g0 + cell;
    const int m    = lane & 3;

    const float* pg = prm + (size_t)g * (NPHY * 4 + 2);

    const float lb[NPHY] = {1.0f, 50.0f, 0.05f, 0.01f, 0.001f, 0.2f, 0.0f, 0.0f, -2.5f, 0.5f, 0.0f, 0.0f};
    const float ub[NPHY] = {6.0f, 1000.0f, 0.9f, 0.5f, 0.2f, 1.0f, 10.0f, 100.0f, 2.5f, 10.0f, 0.1f, 0.2f};
    float ph[NPHY];
    #pragma unroll
    for (int i = 0; i < NPHY; ++i)
        ph[i] = lb[i] + pg[i * 4 + m] * (ub[i] - lb[i]);

    const float beta = ph[0], fc = ph[1], k0 = ph[2], k1 = ph[3], k2 = ph[4],
                lp = ph[5], perc = ph[6], uzl = ph[7], ttp = ph[8],
                cfmax = ph[9], cfr = ph[10], cwh = ph[11];
    const float rfc    = 1.0f / fc;
    const float rlpfc  = 1.0f / (lp * fc);
    const float cfrcf  = cfr * cfmax;
    const float blfc   = beta * __builtin_amdgcn_logf(rfc);  // beta*log2(1/fc)
    const float onemk1 = 1.0f - k1;
    const float onemk2 = 1.0f - k2;

    // Routing weights (gammaln / th^aa cancel under normalization);
    // 0.25 multiplier mean folded in.
    const float aa  = fmaxf(pg[48] * 2.9f, 0.0f) + 0.1f;
    const float th  = fmaxf(pg[49] * 6.5f, 0.0f) + 0.5f;
    const float rth = 1.0f / th;
    const float LOG2E = 1.4426950408889634f;
    float w[LENF];
    float wsum = 0.0f;
    #pragma unroll
    for (int k = 0; k < LENF; ++k) {
        const float tg = (float)k + 0.5f;
        const float e = (aa - 1.0f) * __builtin_log2f(tg) - tg * rth * LOG2E;
        w[k] = __builtin_amdgcn_exp2f(e);
        wsum += w[k];
    }
    const float rw = 0.25f / wsum;
    #pragma unroll
    for (int k = 0; k < LENF; ++k) w[k] *= rw;

    // Per-wave persistent states
    float snowpack = 0.001f, meltwater = 0.001f;   // wave0
    float sm = 0.001f;                             // wave1
    float suz = 0.001f, slz = 0.001f;              // wave2
    float qh[BLK + LENF - 1];                      // wave3: q history (static idx)
    #pragma unroll
    for (int d = 0; d < BLK + LENF - 1; ++d) qh[d] = 0.0f;

    // ---- distributed staging: each wave loads 15 steps of each block ----
    const int loffd = (lane < 48 ? lane : 47);
    const float* ga = xphy + (size_t)(wid * 15) * ROWF + g0 * 3 + loffd;

    // prologue: block 0 into slot 0
    {
        float* ldst = &s_stage[(wid * 15) * SLOTW];
        #pragma unroll
        for (int cc = 0; cc < 15; ++cc) {
            __builtin_amdgcn_global_load_lds((gptr_t)ga, (lptr_t)(ldst + cc * SLOTW), 4, 0, 0);
            ga += ROWF;
        }
        ga += 45 * ROWF;
    }
    asm volatile("s_waitcnt vmcnt(0)" ::: "memory");
    WG_BARRIER();

    for (int i = 0; i <= NBLK + 2; ++i) {
        // ---- stage block i+1 (all waves, 15 loads each) ----
        if (i < NBLK - 1) {
            const int sl = (i + 1) % 3;
            float* ldst = &s_stage[sl * SLOTD + (wid * 15) * SLOTW];
            if (i + 1 == NBLK - 1) {
                // tail block: clamp t at TT-1
                #pragma unroll
                for (int cc = 0; cc < 15; ++cc) {
                    int t = (NBLK - 1) * BLK + wid * 15 + cc;
                    if (t > TT - 1) t = TT - 1;
                    const float* gsrc = xphy + (size_t)t * ROWF + g0 * 3 + loffd;
                    __builtin_amdgcn_global_load_lds((gptr_t)gsrc, (lptr_t)(ldst + cc * SLOTW), 4, 0, 0);
                }
            } else {
                const float* gp2 = ga;
                #pragma unroll
                for (int cc = 0; cc < 15; ++cc) {
                    __builtin_amdgcn_global_load_lds((gptr_t)gp2, (lptr_t)(ldst + cc * SLOTW), 4, 0, 0);
                    gp2 += ROWF;
                }
                ga = gp2 + 45 * ROWF;
            }
        }

        if (wid == 0) {
            // ---- snow chain, block i ----
            if (i < NBLK) {
                const float* sb = &s_stage[(i % 3) * SLOTD + cell * 3];
                f32x2* rtw = &s_rt[(i & 1) * (PAIRS * 64) + lane];
                float rt_even = 0.0f;
                #pragma unroll
                for (int j = 0; j < BLK; ++j) {
                    const float Pt = sb[j * SLOTW];
                    const float Tm = sb[j * SLOTW + 1];
                    const float dT      = Tm - ttp;
                    const float rain    = (Tm >= ttp) ? Pt : 0.0f;
                    const float snow    = Pt - rain;
                    const float meltcap = cfmax * fmaxf(dT, 0.0f);
                    const float refcap  = cfrcf * fmaxf(-dT, 0.0f);
                    snowpack += snow;
                    const float melt = fminf(meltcap, snowpack);
                    meltwater += melt;
                    snowpack  -= melt;
                    const float refreeze = fminf(refcap, meltwater);
                    meltwater -= refreeze;
                    snowpack  += refreeze;
                    const float tosoil = fmaxf(fmaf(-cwh, snowpack, meltwater), 0.0f);
                    meltwater -= tosoil;
                    const float rt = rain + tosoil;
                    if ((j & 1) == 0) rt_even = rt;
                    else {
                        f32x2 pr; pr[0] = rt_even; pr[1] = rt;
                        rtw[(j >> 1) * 64] = pr;
                    }
                }
            }
        } else if (wid == 1) {
            // ---- soil-moisture chain, block i-1 ----
            const int b = i - 1;
            if (b >= 0 && b < NBLK) {
                const float* sb = &s_stage[(b % 3) * SLOTD + cell * 3 + 2];  // ev
                const f32x2* rtr = &s_rt[(b & 1) * (PAIRS * 64) + lane];
                f32x2* rexw = &s_rex[(b & 1) * (PAIRS * 64) + lane];
                f32x2 prt; prt[0] = 0.0f; prt[1] = 0.0f;
                float rex_even = 0.0f;
                #pragma unroll
                for (int j = 0; j < BLK; ++j) {
                    if ((j & 1) == 0) prt = rtr[(j >> 1) * 64];
                    const float rt = ((j & 1) == 0) ? prt[0] : prt[1];
                    const float ev = sb[j * SLOTW];
                    // sw = (sm/fc)^beta = exp2(beta*log2(sm) + beta*log2(1/fc))
                    const float sw    = __builtin_amdgcn_exp2f(fmaf(beta, __builtin_amdgcn_logf(sm), blfc));
                    const float smprt = sm + rt;
                    const float sm1   = fmaf(-rt, sw, smprt);      // sm + rt*(1-sw)
                    const float sm2   = fminf(sm1, fc);
                    const float uf    = fmaxf(fmaf(-ev, rlpfc, 1.0f), 0.0f);  // 1-evapfac
                    const float av    = sm2 * uf;
                    const float cv    = sm2 - ev;
                    sm = fmaxf(fmaxf(av, cv), 1e-5f);              // v_max3
                    const float rex = fmaf(rt, sw, sm1 - sm2);     // recharge + excess
                    if ((j & 1) == 0) rex_even = rex;
                    else {
                        f32x2 pr; pr[0] = rex_even; pr[1] = rex;
                        rexw[(j >> 1) * 64] = pr;
                    }
                }
            }
        } else if (wid == 2) {
            // ---- response chain + quad mean, block i-2 ----
            const int b = i - 2;
            if (b >= 0 && b < NBLK) {
                const f32x2* rexr = &s_rex[(b & 1) * (PAIRS * 64) + lane];
                f32x2* qw = &s_q[(b & 1) * (PAIRS * 64) + lane];
                f32x2 prx; prx[0] = 0.0f; prx[1] = 0.0f;
                float q_even = 0.0f;
                #pragma unroll
                for (int j = 0; j < BLK; ++j) {
                    if ((j & 1) == 0) prx = rexr[(j >> 1) * 64];
                    const float rex = ((j & 1) == 0) ? prx[0] : prx[1];
                    const float suz1 = suz + rex;
                    const float prc  = fminf(suz1, perc);
                    const float suzA = suz1 - prc;
                    const float tq   = fmaxf(suzA - uzl, 0.0f);
                    const float q0   = k0 * tq;
                    const float suzB = fmaf(-k0, tq, suzA);
                    const float q1   = k1 * suzB;
                    suz = suzB * onemk1;
                    const float slz1 = slz + prc;
                    const float q2   = k2 * slz1;
                    slz = slz1 * onemk2;
                    const float q = quad_sum(q0 + q1 + q2);  // *0.25 folded into w
                    if ((j & 1) == 0) q_even = q;
                    else {
                        f32x2 pr; pr[0] = q_even; pr[1] = q;
                        qw[(j >> 1) * 64] = pr;
                    }
                }
            }
        } else {
            // ---- 15-tap routing conv (gather form) + stores, block i-3 ----
            const int b = i - 3;
            if (b >= 0 && b < NBLK) {
                const int t0 = b * BLK;
                const f32x2* qr = &s_q[(b & 1) * (PAIRS * 64) + lane];
                #pragma unroll
                for (int jp = 0; jp < PAIRS; ++jp) {
                    const f32x2 qp = qr[jp * 64];
                    qh[LENF - 1 + 2 * jp]     = qp[0];
                    qh[LENF - 1 + 2 * jp + 1] = qp[1];
                }
                float ov[BLK / 4];
                #pragma unroll
                for (int k = 0; k < BLK / 4; ++k) ov[k] = 0.0f;
                #pragma unroll
                for (int j = 0; j < BLK; ++j) {
                    float o = w[0] * qh[LENF - 1 + j];
                    #pragma unroll
                    for (int k = 1; k < LENF; ++k)
                        o = fmaf(w[k], qh[LENF - 1 + j - k], o);
                    const bool sel = ((j & 3) == m);
                    ov[j >> 2] = sel ? o : ov[j >> 2];     // j>>2 compile-time
                }
                #pragma unroll
                for (int d = 0; d < LENF - 1; ++d) qh[d] = qh[d + BLK];   // static shift
                #pragma unroll
                for (int k = 0; k < BLK / 4; ++k) {
                    const int j = k * 4 + m;
                    const int t = t0 + j;
                    if (t >= WARM && t < TT)
                        out[(size_t)(t - WARM) * NG + g] = ov[k];
                }
            }
        }

        // own staging loads for block i+1 are ~a full iteration old here
        asm volatile("s_waitcnt vmcnt(0)" ::: "memory");
        WG_BARRIER();
    }
}

extern "C" void kernel_launch(void* const* d_in, const int* in_sizes, int n_in,
                              void* d_out, int out_size, void* d_ws, size_t ws_size,
                              hipStream_t stream) {
    const float* xphy = (const float*)d_in[0];   // [2000, 4000, 3]
    const float* prm  = (const float*)d_in[1];   // [1, 4000, 50]
    float* out = (float*)d_out;                  // [1635, 4000, 1]

    hbv_pipe_kernel<<<NG / 16, 256, 0, stream>>>(xphy, prm, out);
}